// Round 6
// baseline (206.098 us; speedup 1.0000x reference)
//
#include <hip/hip_runtime.h>

// ClusterDiceLoss: segmented dice over 64 clusters of a 256^3 volume.
// Memory floor: 201 MB logical read -> ~32 us at 6.3 TB/s.
// History: R3..R8 all 72-78 us across SIX structures: LDS u64 atomics, u32
//   atomics x16 copies, spread global atomics, non-atomic u16 RMW, forced
//   24-deep inline-asm load pipeline. Time invariant to LDS layout, atomic
//   type, DS op count, pipeline depth, occupancy (27%..50%). All pipes idle
//   (VALU<=10%, HBM 16%). => the limiter is OUTSIDE the kernel body: the
//   block->address mapping.
// Channel-phase model: HBM channel ~ (addr>>12)%128 (R2's 8MB-stride 5.6x
//   regression proves pow2 interleave). Contiguous 64KB chunks: group g of
//   block b -> channel (16b+g)%128. Equal-work blocks progress in LOCKSTEP
//   through g=0..15, so at any instant the chip uses only 8-32 of 128
//   channels -> ~1-2 TB/s ceiling. Measured 1.33 TB/s HBM. Explains every
//   invariance: nothing inside the loop changes which channels are hot.
//   The 3 arrays are 64MB apart (0 mod 512KB) -> same channel set, x3.
// R9: de-phase. Block b sweeps its 16 groups starting at g0=(b>>3)&15,
//   wrapping mod 16 -> instantaneous channel set {16(b%8)+(b>>3)+phase} =
//   ALL 128 residues, always. Pipeline simplified to 2-deep x 1-group
//   (6 loads in flight, 24 data VGPRs, no spill risk; R8 proved deeper
//   buys nothing). Everything else (u16 private columns, cascaded-merge
//   RMW, SWAR fold, replicated global slots) verified in R6-R8.

#define NBIN 65          // bins 0..64 (bin 0 = background, dropped at fold)
#define NREP 64          // replicated global partial slots
#define REP_MASK 63
#define BLOCKS 1024
#define THREADS 256

typedef float4 f4;
typedef int4 i4;

// one 16-B load, 32-bit voffset + 64-bit SGPR base; volatile => pinned.
#define GLOAD(dst, voff, base) \
    asm volatile("global_load_dwordx4 %0, %1, %2" \
                 : "=v"(dst) : "v"(voff), "s"(base))

// wait for all but the newest NSTR outstanding vector loads, then fence the
// scheduler so no consumer is hoisted above the wait (rule #18).
#define WAITN(NSTR) do { \
    asm volatile("s_waitcnt vmcnt(" NSTR ")" ::: "memory"); \
    __builtin_amdgcn_sched_barrier(0); \
} while (0)

// issue one group's 3 loads (pred/target/labels) for rotated group g
#define ISSUE1(X, g) do { \
    unsigned int vo = vbase + (((unsigned int)(g)) & 15u) * 4096u; \
    GLOAD(P##X, vo, pred); GLOAD(T##X, vo, target); GLOAD(L##X, vo, labels); \
} while (0)

#define PROC(X) rmw_group(hist, tid, P##X, T##X, L##X)

// per-element u16 contribution: inter<<8 | (sp+st). 64 elems/thread ->
// union field <= 128 < 256, inter <= 64. No carry.
__device__ __forceinline__ unsigned int contrib(float p, float t) {
    unsigned int sp = (p != 0.0f) ? 1u : 0u;
    unsigned int st = (t != 0.0f) ? 1u : 0u;
    return ((sp & st) << 8) | (sp + st);
}

// Batched-read cascaded-merge RMW into this thread's private column
// ([bin][thread] u16; sole writer of its cells). All 4 reads precede all 4
// writes (one lgkmcnt exposure per 4 elements). Duplicate labels within the
// group: each later duplicate's write carries the cumulative sum (e-cascade);
// same-wave DS ops retire in order, so the last write is the correct total.
__device__ __forceinline__ void rmw_group(unsigned short* hist, int tid,
                                          f4 p, f4 t, i4 l) {
    const int i0 = l.x * THREADS + tid;
    const int i1 = l.y * THREADS + tid;
    const int i2 = l.z * THREADS + tid;
    const int i3 = l.w * THREADS + tid;
    const unsigned int d0 = hist[i0];
    const unsigned int d1 = hist[i1];
    const unsigned int d2 = hist[i2];
    const unsigned int d3 = hist[i3];
    const unsigned int c0 = contrib(p.x, t.x);
    const unsigned int c1 = contrib(p.y, t.y);
    const unsigned int c2 = contrib(p.z, t.z);
    const unsigned int c3 = contrib(p.w, t.w);
    const unsigned int e0 = c0;
    const unsigned int e1 = c1 + ((i1 == i0) ? e0 : 0u);
    const unsigned int e2 = c2 + ((i2 == i1) ? e1 : ((i2 == i0) ? e0 : 0u));
    const unsigned int e3 = c3 + ((i3 == i2) ? e2 :
                             ((i3 == i1) ? e1 : ((i3 == i0) ? e0 : 0u)));
    hist[i0] = (unsigned short)(d0 + e0);
    hist[i1] = (unsigned short)(d1 + e1);
    hist[i2] = (unsigned short)(d2 + e2);
    hist[i3] = (unsigned short)(d3 + e3);
}

__global__ __launch_bounds__(THREADS, 4) void seg_count_kernel(
    const float* __restrict__ pred,
    const float* __restrict__ target,
    const int* __restrict__ labels,
    unsigned long long* __restrict__ part,   // [64][NREP] packed u64, zeroed
    int n)
{
    __shared__ unsigned short s_hist[NBIN][THREADS];   // 33280 B -> 4 blk/CU
    const int tid = threadIdx.x;
    const int rep = (int)blockIdx.x & REP_MASK;
    unsigned short* hist = &s_hist[0][0];

    unsigned int* hz = (unsigned int*)s_hist;
    for (int i = tid; i < NBIN * THREADS / 2; i += THREADS) hz[i] = 0u;
    __syncthreads();

    const int n_vec = n >> 2;  // float4 groups
    const int chunk = (n_vec + (int)gridDim.x - 1) / (int)gridDim.x;
    const int base = blockIdx.x * chunk;
    const int end = min(base + chunk, n_vec);

    if (end - base == 16 * THREADS) {
        // ---- fast path: 16 groups/thread, rotated order, 2-deep pipe ----
        // rotation phase: varies with b>>3 so that {chunk-channel (16b%128)}
        // x {phase} covers all 128 channel residues at every instant.
        const int g0 = ((int)blockIdx.x >> 3) & 15;
        const unsigned int vbase = (unsigned int)(base + tid) * 16u;
        f4 PA, TA, PB, TB;
        i4 LA, LB;

        ISSUE1(A, g0);           // group 0 in flight (3 loads)
        ISSUE1(B, g0 + 1);       // group 1 in flight (6 loads)
        #pragma unroll
        for (int j = 0; j < 16; j += 2) {
            WAITN("3");                          // A's 3 done, B's 3 remain
            PROC(A);
            if (j + 2 < 16) ISSUE1(A, g0 + j + 2);
            if (j + 3 < 16) { WAITN("3"); } else { WAITN("0"); }
            PROC(B);
            if (j + 3 < 16) ISSUE1(B, g0 + j + 3);
        }
    } else {
        // ---- generic fallback (not hit at n = 256^3 / 1024 blocks) ----
        const f4* __restrict__ p4 = (const f4*)pred;
        const f4* __restrict__ t4 = (const f4*)target;
        const i4* __restrict__ l4 = (const i4*)labels;
        for (int idx = base + tid; idx < end; idx += THREADS)
            rmw_group(hist, tid, p4[idx], t4[idx], l4[idx]);
    }

    // scalar tail (n not divisible by 4): block 0 only; private column
    if (blockIdx.x == 0) {
        for (int i = (n_vec << 2) + tid; i < n; i += THREADS)
            hist[labels[i] * THREADS + tid] =
                (unsigned short)(hist[labels[i] * THREADS + tid] +
                                 contrib(pred[i], target[i]));
    }
    __syncthreads();

    // Fold: bins 1..64 x 4 quarter-threads (bin 0 dropped -> exactly 256).
    // 16 u64 reads (4 u16 each), SWAR 16-bit lanes: 16 iters x 255 < 65536.
    const int s = 1 + (tid >> 2);
    const int q = tid & 3;
    const unsigned long long* row =
        (const unsigned long long*)&s_hist[s][q * 64];
    unsigned long long accU = 0, accI = 0;
    const int rot = tid & 15;   // rotate start to dodge lockstep banking
    #pragma unroll
    for (int j = 0; j < 16; ++j) {
        int i = (j + rot) & 15;
        unsigned long long v = row[i];
        accU += v & 0x00FF00FF00FF00FFull;
        accI += (v >> 8) & 0x00FF00FF00FF00FFull;
    }
    accU += accU >> 32;   // u16 lanes <= 8160: no cross-lane carry
    accI += accI >> 32;
    unsigned int U = ((unsigned int)accU & 0xFFFFu) + (((unsigned int)accU >> 16) & 0xFFFFu);
    unsigned int I = ((unsigned int)accI & 0xFFFFu) + (((unsigned int)accI >> 16) & 0xFFFFu);

    U += __shfl_xor(U, 1); U += __shfl_xor(U, 2);
    I += __shfl_xor(I, 1); I += __shfl_xor(I, 2);
    if (q == 0) {
        unsigned long long tot =
            ((unsigned long long)I << 32) | (unsigned long long)U;
        if (tot) atomicAdd(&part[(s - 1) * NREP + rep], tot);
    }
}

__global__ __launch_bounds__(256) void dice_finalize_kernel(
    const unsigned long long* __restrict__ part,   // [64][NREP]
    const int* __restrict__ nc_ptr,
    float* __restrict__ out)
{
    const int nc = *nc_ptr;          // 64
    const int tid = threadIdx.x;
    const int s = 1 + (tid >> 2);
    const int q = tid & 3;

    unsigned long long acc = 0;
    const unsigned long long* row = part + (s - 1) * NREP + q * 16;
    #pragma unroll
    for (int i = 0; i < 16; ++i) acc += row[i];
    acc += __shfl_xor(acc, 1);
    acc += __shfl_xor(acc, 2);

    __shared__ float s_dice[64];
    if (q == 0) {
        float U = (float)(unsigned int)(acc & 0xFFFFFFFFull);
        float I = (float)(unsigned int)(acc >> 32);
        float dice = (U > 0.0f) ? (2.0f * I / U) : 1.0f;
        s_dice[s - 1] = (s <= nc) ? dice : 0.0f;
    }
    __syncthreads();

    if (tid < 64) {
        float local = s_dice[tid];
        #pragma unroll
        for (int off = 32; off > 0; off >>= 1)
            local += __shfl_down(local, off);
        if (tid == 0) out[0] = 1.0f - local / (float)nc;
    }
}

extern "C" void kernel_launch(void* const* d_in, const int* in_sizes, int n_in,
                              void* d_out, int out_size, void* d_ws, size_t ws_size,
                              hipStream_t stream) {
    const float* pred   = (const float*)d_in[0];
    const float* target = (const float*)d_in[1];
    const int*   labels = (const int*)d_in[2];
    const int*   nc_ptr = (const int*)d_in[3];
    float* out = (float*)d_out;
    unsigned long long* part = (unsigned long long*)d_ws;

    const int n = in_sizes[0];

    hipMemsetAsync(d_ws, 0, 64 * NREP * sizeof(unsigned long long), stream);

    seg_count_kernel<<<BLOCKS, THREADS, 0, stream>>>(
        pred, target, labels, part, n);
    dice_finalize_kernel<<<1, 256, 0, stream>>>(part, nc_ptr, out);
}

// Round 7
// 200.497 us; speedup vs baseline: 1.0279x; 1.0279x over previous
//
#include <hip/hip_runtime.h>

// ClusterDiceLoss: segmented dice over 64 clusters of a 256^3 volume.
// 201 MB read-only. History: R3..R9, seven structures, all 72-81 us.
// Time invariant to: LDS layout/atomics/DS-op count (R3=R4=R6), global-atomic
//   contention (R5), forced 24-deep load pipeline (R8), channel phasing
//   (R9, -5% -> reverted), occupancy 27..50%.
// Unifying model (fits all rounds + m13): per-CU in-flight-miss cap ~4 KB
//   (MSHR-limited MLP) / ~950 cyc mixed L3-HBM latency = ~4.3 B/cyc/CU.
//   Constant across rounds: 768 wave-loads/CU x ~240 cyc = 185k cyc = 77 us.
//   m13's 6.29 TB/s copy = 3.15 TB/s READ component = 5.1 B/cyc/CU; our best
//   (R5, 72.8 us) = 2.79 TB/s read-only = 89% of that.
// R10 discriminator: if any of the cap is per-WAVE (vmcnt depth x waves),
//   more resident waves = more in-flight bytes. All 72-73 us results were
//   8 blk/CU; 76-81 us were 4 blk/CU. So: 4096 blocks, launch_bounds(256,8)
//   -> VGPR<=64 -> 32 waves/CU (2x previous best). Small 4.6 KB LDS so LDS
//   never caps occupancy. Plain C++ double-buffered loads (forced-asm proven
//   equal, R8). If time unchanged at ~2x occupancy -> per-CU cap confirmed
//   -> declare roofline next round.

#define NSEG 65          // clusters 0..64 (0 = background, dropped)
#define NREP 64          // replicated global partial slots (R5)
#define REP_MASK 63
#define NCOPY 16         // LDS histogram copies (one per 16 lanes)
#define BLOCKS 4096
#define THREADS 256
#define GP 4             // float4-groups per thread (chunk = 1024)

// Per-element u32 contribution: inter<<20 | sp<<10 | st.
// Bounds per LDS copy: 16 lanes x (GP*4 = 16 elems) = 256 max < 1023. Safe.
__device__ __forceinline__ unsigned int pack32(float p, float t) {
    unsigned int sp = (p != 0.0f) ? 1u : 0u;
    unsigned int st = (t != 0.0f) ? 1u : 0u;
    return ((sp & st) << 20) | (sp << 10) | st;
}

__device__ __forceinline__ void accum4(unsigned int (*s_cnt)[NSEG], int copy,
                                       float4 p, float4 t, int4 l) {
    atomicAdd(&s_cnt[copy][l.x], pack32(p.x, t.x));
    atomicAdd(&s_cnt[copy][l.y], pack32(p.y, t.y));
    atomicAdd(&s_cnt[copy][l.z], pack32(p.z, t.z));
    atomicAdd(&s_cnt[copy][l.w], pack32(p.w, t.w));
}

__global__ __launch_bounds__(THREADS, 8) void seg_count_kernel(
    const float* __restrict__ pred,
    const float* __restrict__ target,
    const int* __restrict__ labels,
    unsigned long long* __restrict__ part,   // [NSEG][NREP] packed u64, zeroed
    int n)
{
    __shared__ unsigned int s_cnt[NCOPY][NSEG];   // 4160 B
    const int tid = threadIdx.x;
    const int copy = tid >> 4;
    const int rep = (int)blockIdx.x & REP_MASK;

    for (int i = tid; i < NCOPY * NSEG; i += THREADS)
        ((unsigned int*)s_cnt)[i] = 0u;
    __syncthreads();

    const int n_vec = n >> 2;  // float4 groups
    const float4* __restrict__ p4 = (const float4*)pred;
    const float4* __restrict__ t4 = (const float4*)target;
    const int4*   __restrict__ l4 = (const int4*)labels;

    // contiguous chunk per block: 1024 groups -> GP=4 per thread.
    const int chunk = (n_vec + (int)gridDim.x - 1) / (int)gridDim.x;
    const int base = blockIdx.x * chunk;
    const int end = min(base + chunk, n_vec);

    if (end - base == GP * THREADS) {
        // fast path: double-buffered, compiler-scheduled (proven equal to
        // forced asm in R8; keep VGPR <= 64 for 8 waves/EU).
        int idx = base + tid;
        float4 pa = p4[idx];
        float4 ta = t4[idx];
        int4   la = l4[idx];
        #pragma unroll
        for (int g = 1; g < GP; ++g) {
            float4 pb = p4[idx + g * THREADS];
            float4 tb = t4[idx + g * THREADS];
            int4   lb = l4[idx + g * THREADS];
            accum4(s_cnt, copy, pa, ta, la);
            pa = pb; ta = tb; la = lb;
        }
        accum4(s_cnt, copy, pa, ta, la);
    } else {
        for (int idx = base + tid; idx < end; idx += THREADS)
            accum4(s_cnt, copy, p4[idx], t4[idx], l4[idx]);
    }

    // scalar tail (n not divisible by 4): block 0 only
    if (blockIdx.x == 0) {
        for (int i = (n_vec << 2) + tid; i < n; i += THREADS)
            atomicAdd(&s_cnt[copy][labels[i]], pack32(pred[i], target[i]));
    }
    __syncthreads();

    // fold 16 u32 copies -> one packed u64 global atomic per segment into
    // this block's replica. Per-replica field sums: 64 blocks x 4096 max
    // = 262k < 2^21 -> no carry in the 21-bit u64 fields.
    for (int s = tid; s < NSEG; s += THREADS) {
        unsigned long long in = 0, sp = 0, st = 0;
        #pragma unroll
        for (int c = 0; c < NCOPY; ++c) {
            unsigned int v = s_cnt[c][s];
            st += v & 0x3FFu;
            sp += (v >> 10) & 0x3FFu;
            in += v >> 20;
        }
        unsigned long long tot = (in << 42) | (sp << 21) | st;
        if (tot) atomicAdd(&part[s * NREP + rep], tot);
    }
}

__global__ __launch_bounds__(256) void dice_finalize_kernel(
    const unsigned long long* __restrict__ part,   // [NSEG][NREP]
    const int* __restrict__ nc_ptr,
    float* __restrict__ out)
{
    const int nc = *nc_ptr;          // 64
    const int tid = threadIdx.x;
    // 4 threads per segment, segments 1..64 (segment 0 = background).
    const int s = 1 + (tid >> 2);
    const int q = tid & 3;

    unsigned long long acc = 0;
    const unsigned long long* row = part + s * NREP + q * 16;
    #pragma unroll
    for (int i = 0; i < 16; ++i) acc += row[i];
    acc += __shfl_xor(acc, 1);
    acc += __shfl_xor(acc, 2);

    __shared__ float s_dice[64];
    if (q == 0) {
        float in = (float)(acc >> 42);
        float sp = (float)((acc >> 21) & 0x1FFFFFull);
        float st = (float)(acc & 0x1FFFFFull);
        float uni = sp + st;
        float dice = (uni > 0.0f) ? (2.0f * in / uni) : 1.0f;
        s_dice[s - 1] = (s <= nc) ? dice : 0.0f;
    }
    __syncthreads();

    if (tid < 64) {
        float local = s_dice[tid];
        #pragma unroll
        for (int off = 32; off > 0; off >>= 1)
            local += __shfl_down(local, off);
        if (tid == 0) out[0] = 1.0f - local / (float)nc;
    }
}

extern "C" void kernel_launch(void* const* d_in, const int* in_sizes, int n_in,
                              void* d_out, int out_size, void* d_ws, size_t ws_size,
                              hipStream_t stream) {
    const float* pred   = (const float*)d_in[0];
    const float* target = (const float*)d_in[1];
    const int*   labels = (const int*)d_in[2];
    const int*   nc_ptr = (const int*)d_in[3];
    float* out = (float*)d_out;
    unsigned long long* part = (unsigned long long*)d_ws;

    const int n = in_sizes[0];

    hipMemsetAsync(d_ws, 0, NSEG * NREP * sizeof(unsigned long long), stream);

    seg_count_kernel<<<BLOCKS, THREADS, 0, stream>>>(
        pred, target, labels, part, n);
    dice_finalize_kernel<<<1, 256, 0, stream>>>(part, nc_ptr, out);
}